// Round 7
// baseline (619.757 us; speedup 1.0000x reference)
//
#include <hip/hip_runtime.h>

// HexagonalSensor photon binning — R5: three-way A/B/C ablation on real work.
// A: LDS lut gather + LDS atomic (control, = R4 structure), photons [0, n/4)
// B: closed-form pixel id + LDS atomic,                     photons [n/4, n/2)
// C: closed-form pixel id + global atomics to 32 replicas,  photons [n/2, n)
// All photons counted exactly once; reduce sums A/B partial rows + C replicas.
// Theory under test: LDS atomic pipe serializes per-lane (~2cyc/lane) ->
// ~131K cyc/CU, explaining the invariant 105us with all pipes <15% busy.

#define NPIX   1801      // 3*R*(R+1)+1 for R=24
#define RINGS  24
#define HEXW   (2 * RINGS + 1)       // 49
#define LUTQ   49
#define LUTR   49
#define LUTN   (LUTQ * LUTR)
#define TPB    256
#define NREP   32        // global replica histograms for variant C
#define GROUPS 16        // reduction groups

// ---------- shared device helpers ----------

__device__ __forceinline__ void affine_setup(
    float hs, float rot, float ox, float oy,
    float& Aq, float& Bq, float& Ar, float& Br, float& Cq, float& Cr)
{
    const float ca = cosf(-rot);
    const float sa = sinf(-rot);
    const float k1 = sqrtf(3.0f) / 3.0f;
    const float inv_hs = 1.0f / hs;
    Aq = (k1 * ca - sa * (1.0f / 3.0f)) * inv_hs;
    Bq = (-k1 * sa - ca * (1.0f / 3.0f)) * inv_hs;
    Ar = ((2.0f / 3.0f) * sa) * inv_hs;
    Br = ((2.0f / 3.0f) * ca) * inv_hs;
    Cq = -(Aq * ox + Bq * oy);
    Cr = -(Ar * ox + Br * oy);
}

__device__ __forceinline__ void axial_round(float q, float r, int& qi, int& ri)
{
    const float s = -q - r;
    const float qr0 = rintf(q);   // v_rndne, round-half-even like jnp.round
    const float rr0 = rintf(r);
    const float sr0 = rintf(s);
    const float qd = fabsf(qr0 - q);
    const float rd = fabsf(rr0 - r);
    const float sd = fabsf(sr0 - s);
    const bool c1 = (qd > rd) && (qd > sd);
    const bool c2 = (rd > qd) && (rd > sd);
    qi = (int)(c1 ? (-rr0 - sr0) : qr0);
    ri = (int)(c2 ? (-qr0 - sr0) : rr0);
}

// closed-form pixel id matching the reference enumeration
// (q from -R..R, r from max(-R,-q-R)..min(R,-q+R)); verified analytically:
// offset(q) = (q+R)(2R+1) - sum|q'|, sum|q'| = [R(R+1) + (q>0? q(q-1) : -q(q-1))]/2
// id(-24,0)=0, id(-24,24)=24, id(-23,-1)=25, id(0,0)=900, id(24,0)=1800.
__device__ __forceinline__ int hex_id(int qi, int ri, bool& valid)
{
    valid = (abs(qi) <= RINGS) && (abs(ri) <= RINGS) && (abs(qi + ri) <= RINGS);
    const int t = qi * (qi - 1);                        // always even
    const int sumabs = (RINGS * (RINGS + 1) + (qi > 0 ? t : -t)) >> 1;
    const int off = (qi + RINGS) * HEXW - sumabs;
    const int rlo = (qi <= 0) ? (-qi - RINGS) : -RINGS;
    return off + ri - rlo;
}

// ---------- init: zero output + replica histograms ----------

__global__ __launch_bounds__(TPB) void hex_init_kernel(
    float* __restrict__ out, float* __restrict__ reps,
    const int* __restrict__ p_np)
{
    const int np = p_np[0];
    const int stride = gridDim.x * TPB;
    for (int i = blockIdx.x * TPB + threadIdx.x; i < np; i += stride)
        out[i] = 0.0f;
    for (int i = blockIdx.x * TPB + threadIdx.x; i < NREP * NPIX; i += stride)
        reps[i] = 0.0f;
}

// ---------- variant A: LDS lut gather + LDS atomic (control) ----------

__global__ __launch_bounds__(TPB) void hex_hist_A(
    const float* __restrict__ gx, const float* __restrict__ gy,
    const float* __restrict__ gv, const int* __restrict__ glut,
    const float* __restrict__ p_hs, const float* __restrict__ p_rot,
    const float* __restrict__ p_ox, const float* __restrict__ p_oy,
    const int* __restrict__ p_qmin, const int* __restrict__ p_rmin,
    float* __restrict__ partials, int p0, int p1)
{
    __shared__ float hist[NPIX];
    __shared__ int   lut[LUTN];
    const int tid = threadIdx.x;
    for (int i = tid; i < NPIX; i += TPB) hist[i] = 0.0f;
    for (int i = tid; i < LUTN; i += TPB) lut[i] = glut[i];
    __syncthreads();

    float Aq, Bq, Ar, Br, Cq, Cr;
    affine_setup(p_hs[0], p_rot[0], p_ox[0], p_oy[0], Aq, Bq, Ar, Br, Cq, Cr);
    const int qmin = p_qmin[0];
    const int rmin = p_rmin[0];

    auto bin_one = [&](float px, float py, float pv) {
        const float q = fmaf(Aq, px, fmaf(Bq, py, Cq));
        const float r = fmaf(Ar, px, fmaf(Br, py, Cr));
        int qi, ri;  axial_round(q, r, qi, ri);
        const int qx = qi - qmin, rx = ri - rmin;
        if ((unsigned)qx < LUTQ && (unsigned)rx < LUTR) {
            const int p = lut[qx * LUTR + rx];
            if (p >= 0) unsafeAtomicAdd(&hist[p], pv);
        }
    };

    const int gthreads = gridDim.x * TPB;
    const int gtid     = blockIdx.x * TPB + tid;
    const int v0 = p0 >> 2, v1 = p1 >> 2;
    const float4* x4 = (const float4*)gx;
    const float4* y4 = (const float4*)gy;
    const float4* v4 = (const float4*)gv;
    for (int i = v0 + gtid; i < v1; i += gthreads) {
        float4 a = x4[i], b = y4[i], v = v4[i];
        bin_one(a.x, b.x, v.x); bin_one(a.y, b.y, v.y);
        bin_one(a.z, b.z, v.z); bin_one(a.w, b.w, v.w);
    }
    for (int t = (v1 << 2) + gtid; t < p1; t += gthreads)
        bin_one(gx[t], gy[t], gv[t]);

    __syncthreads();
    float* prow = partials + (size_t)blockIdx.x * NPIX;
    for (int p = tid; p < NPIX; p += TPB) prow[p] = hist[p];
}

// ---------- variant B: closed-form id + LDS atomic ----------

__global__ __launch_bounds__(TPB) void hex_hist_B(
    const float* __restrict__ gx, const float* __restrict__ gy,
    const float* __restrict__ gv,
    const float* __restrict__ p_hs, const float* __restrict__ p_rot,
    const float* __restrict__ p_ox, const float* __restrict__ p_oy,
    float* __restrict__ partials, int p0, int p1)
{
    __shared__ float hist[NPIX];
    const int tid = threadIdx.x;
    for (int i = tid; i < NPIX; i += TPB) hist[i] = 0.0f;
    __syncthreads();

    float Aq, Bq, Ar, Br, Cq, Cr;
    affine_setup(p_hs[0], p_rot[0], p_ox[0], p_oy[0], Aq, Bq, Ar, Br, Cq, Cr);

    auto bin_one = [&](float px, float py, float pv) {
        const float q = fmaf(Aq, px, fmaf(Bq, py, Cq));
        const float r = fmaf(Ar, px, fmaf(Br, py, Cr));
        int qi, ri;  axial_round(q, r, qi, ri);
        bool valid;  const int id = hex_id(qi, ri, valid);
        if (valid) unsafeAtomicAdd(&hist[id], pv);
    };

    const int gthreads = gridDim.x * TPB;
    const int gtid     = blockIdx.x * TPB + tid;
    const int v0 = p0 >> 2, v1 = p1 >> 2;
    const float4* x4 = (const float4*)gx;
    const float4* y4 = (const float4*)gy;
    const float4* v4 = (const float4*)gv;
    for (int i = v0 + gtid; i < v1; i += gthreads) {
        float4 a = x4[i], b = y4[i], v = v4[i];
        bin_one(a.x, b.x, v.x); bin_one(a.y, b.y, v.y);
        bin_one(a.z, b.z, v.z); bin_one(a.w, b.w, v.w);
    }
    for (int t = (v1 << 2) + gtid; t < p1; t += gthreads)
        bin_one(gx[t], gy[t], gv[t]);

    __syncthreads();
    float* prow = partials + (size_t)blockIdx.x * NPIX;
    for (int p = tid; p < NPIX; p += TPB) prow[p] = hist[p];
}

// ---------- variant C: closed-form id + global atomics to 32 replicas ----------

__global__ __launch_bounds__(TPB) void hex_hist_C(
    const float* __restrict__ gx, const float* __restrict__ gy,
    const float* __restrict__ gv,
    const float* __restrict__ p_hs, const float* __restrict__ p_rot,
    const float* __restrict__ p_ox, const float* __restrict__ p_oy,
    float* __restrict__ reps, int p0, int p1)
{
    float Aq, Bq, Ar, Br, Cq, Cr;
    affine_setup(p_hs[0], p_rot[0], p_ox[0], p_oy[0], Aq, Bq, Ar, Br, Cq, Cr);
    float* rep = reps + (size_t)(blockIdx.x & (NREP - 1)) * NPIX;

    auto bin_one = [&](float px, float py, float pv) {
        const float q = fmaf(Aq, px, fmaf(Bq, py, Cq));
        const float r = fmaf(Ar, px, fmaf(Br, py, Cr));
        int qi, ri;  axial_round(q, r, qi, ri);
        bool valid;  const int id = hex_id(qi, ri, valid);
        if (valid) unsafeAtomicAdd(&rep[id], pv);   // global_atomic_add_f32
    };

    const int gthreads = gridDim.x * TPB;
    const int gtid     = blockIdx.x * TPB + threadIdx.x;
    const int v0 = p0 >> 2, v1 = p1 >> 2;
    const float4* x4 = (const float4*)gx;
    const float4* y4 = (const float4*)gy;
    const float4* v4 = (const float4*)gv;
    for (int i = v0 + gtid; i < v1; i += gthreads) {
        float4 a = x4[i], b = y4[i], v = v4[i];
        bin_one(a.x, b.x, v.x); bin_one(a.y, b.y, v.y);
        bin_one(a.z, b.z, v.z); bin_one(a.w, b.w, v.w);
    }
    for (int t = (v1 << 2) + gtid; t < p1; t += gthreads)
        bin_one(gx[t], gy[t], gv[t]);
}

// ---------- reduce: out[p] = sum over partial rows (A,B) + replicas (C) ----------

__global__ __launch_bounds__(TPB) void hex_reduce_kernel(
    const float* __restrict__ rows, float* __restrict__ out,
    const int* __restrict__ p_np, int totrows, int rows_per_group)
{
    const int np = p_np[0];
    const int p  = blockIdx.x * TPB + threadIdx.x;
    if (p >= np || p >= NPIX) return;
    const int row0 = blockIdx.y * rows_per_group;
    float sum = 0.0f;
    for (int b = 0; b < rows_per_group; ++b) {
        const int row = row0 + b;
        if (row < totrows) sum += rows[(size_t)row * NPIX + p];
    }
    atomicAdd(&out[p], sum);
}

extern "C" void kernel_launch(void* const* d_in, const int* in_sizes, int n_in,
                              void* d_out, int out_size, void* d_ws, size_t ws_size,
                              hipStream_t stream) {
    const float* x    = (const float*)d_in[0];
    const float* y    = (const float*)d_in[1];
    const float* vals = (const float*)d_in[2];
    const int*   lut  = (const int*)d_in[3];
    const float* hs   = (const float*)d_in[4];
    const float* rot  = (const float*)d_in[5];
    const float* offx = (const float*)d_in[6];
    const float* offy = (const float*)d_in[7];
    const int*   qmin = (const int*)d_in[8];
    const int*   rmin = (const int*)d_in[9];
    const int*   npix = (const int*)d_in[10];
    float*       out  = (float*)d_out;
    const int    n    = in_sizes[0];

    // workspace layout: [nA rows | nB rows | NREP replica rows], each NPIX f32
    int nA = 1024, nB = 1024;
    const size_t row_bytes = (size_t)NPIX * sizeof(float);
    if (ws_size < (size_t)(nA + nB + NREP) * row_bytes) {
        int tot = (int)(ws_size / row_bytes) - NREP;
        if (tot < 32) tot = 32;
        nA = nB = tot / 2;
    }
    float* parts = (float*)d_ws;
    float* reps  = parts + (size_t)(nA + nB) * NPIX;

    // photon ranges: quarters must be multiples of 4 for the float4 path
    const int n4  = (n >> 2) & ~3;
    const int q1  = n4;          // A: [0, q1)
    const int q2  = 2 * n4;      // B: [q1, q2);  C: [q2, n)

    hipLaunchKernelGGL(hex_init_kernel, dim3(64), dim3(TPB), 0, stream,
                       out, reps, npix);

    hipLaunchKernelGGL(hex_hist_A, dim3(nA), dim3(TPB), 0, stream,
                       x, y, vals, lut, hs, rot, offx, offy, qmin, rmin,
                       parts, 0, q1);

    hipLaunchKernelGGL(hex_hist_B, dim3(nB), dim3(TPB), 0, stream,
                       x, y, vals, hs, rot, offx, offy,
                       parts + (size_t)nA * NPIX, q1, q2);

    hipLaunchKernelGGL(hex_hist_C, dim3(1024), dim3(TPB), 0, stream,
                       x, y, vals, hs, rot, offx, offy,
                       reps, q2, n);

    const int totrows = nA + nB + NREP;
    const int rows_per_group = (totrows + GROUPS - 1) / GROUPS;
    hipLaunchKernelGGL(hex_reduce_kernel,
                       dim3((NPIX + TPB - 1) / TPB, GROUPS), dim3(TPB), 0, stream,
                       parts, out, npix, totrows, rows_per_group);
}